// Round 1
// baseline (71.130 us; speedup 1.0000x reference)
//
#include <hip/hip_runtime.h>

#define F_ALPHA 0.25f
#define F_EPS 1e-4f

constexpr int B = 16, N = 100000, C = 10, M = 32;
constexpr int BPB = 64;        // blocks per batch
constexpr int THREADS = 256;

// ws layout: partials[B][BPB][3] floats = (cls_sum, reg_sum, pos_cnt)

__global__ __launch_bounds__(THREADS) void focal_main(
    const float* __restrict__ cls,    // [B][N][C]
    const float* __restrict__ reg,    // [B][N][4]
    const float* __restrict__ anc,    // [B][N][4]
    const float* __restrict__ ann,    // [B][M][5]
    float* __restrict__ partials)
{
    const int b   = blockIdx.x / BPB;
    const int blk = blockIdx.x % BPB;

    __shared__ float4 s_box[M];
    __shared__ float  s_area[M];
    __shared__ float  s_lab[M];

    if (threadIdx.x < M) {
        const int m = threadIdx.x;
        const float* a = ann + ((size_t)b * M + m) * 5;
        float4 bx = make_float4(a[0], a[1], a[2], a[3]);
        s_box[m]  = bx;
        s_area[m] = (bx.z - bx.x) * (bx.w - bx.y);
        s_lab[m]  = a[4];
    }
    __syncthreads();

    float cls_sum = 0.f, reg_sum = 0.f, pos_cnt = 0.f;

    const size_t baseN = (size_t)b * N;
    for (int n = blk * THREADS + threadIdx.x; n < N; n += BPB * THREADS) {
        const float4 a4 = *reinterpret_cast<const float4*>(anc + (baseN + n) * 4);
        const float aw = a4.z - a4.x;
        const float ah = a4.w - a4.y;
        const float area_a = aw * ah;

        // IoU max/argmax over 32 GT boxes (first-max semantics)
        float best = -2.f;
        int   barg = 0;
        #pragma unroll 8
        for (int m = 0; m < M; ++m) {
            const float4 bx = s_box[m];
            const float iw = fminf(a4.z, bx.z) - fmaxf(a4.x, bx.x);
            const float ih = fminf(a4.w, bx.w) - fmaxf(a4.y, bx.y);
            const float inter = fmaxf(iw, 0.f) * fmaxf(ih, 0.f);
            const float uni = fmaxf(area_a + s_area[m] - inter, 1e-8f);
            float iou = __fdividef(inter, uni);
            iou = (s_lab[m] != -1.0f) ? iou : -1.0f;
            if (iou > best) { best = iou; barg = m; }
        }

        const bool pos = best >= 0.5f;
        const bool bg  = best <  0.4f;

        if (pos || bg) {
            const int tcls = pos ? (int)s_lab[barg] : -1;
            const float2* cp2 = reinterpret_cast<const float2*>(cls + (baseN + n) * C);
            float pv[C];
            #pragma unroll
            for (int j2 = 0; j2 < C / 2; ++j2) {
                const float2 v = cp2[j2];
                pv[2 * j2]     = v.x;
                pv[2 * j2 + 1] = v.y;
            }
            float lsum = 0.f;
            #pragma unroll
            for (int j = 0; j < C; ++j) {
                float p = fminf(fmaxf(pv[j], F_EPS), 1.f - F_EPS);
                float w, bce;
                if (j == tcls) {
                    const float q = 1.f - p;
                    w   = F_ALPHA * q * q;
                    bce = -__logf(p);
                } else {
                    w   = (1.f - F_ALPHA) * p * p;
                    bce = -__logf(1.f - p);
                }
                lsum += w * bce;
            }
            cls_sum += lsum;
        }

        if (pos) {
            pos_cnt += 1.f;
            const float4 g = s_box[barg];
            float gw = g.z - g.x, gh = g.w - g.y;
            const float gcx = g.x + 0.5f * gw, gcy = g.y + 0.5f * gh;
            const float acx = a4.x + 0.5f * aw, acy = a4.y + 0.5f * ah;
            gw = fmaxf(gw, 1.f);
            gh = fmaxf(gh, 1.f);
            const float t0 = __fdividef(gcx - acx, aw) * 10.f;   // / 0.1
            const float t1 = __fdividef(gcy - acy, ah) * 10.f;
            const float t2 = __logf(__fdividef(gw, aw)) * 5.f;   // / 0.2
            const float t3 = __logf(__fdividef(gh, ah)) * 5.f;
            const float4 r4 = *reinterpret_cast<const float4*>(reg + (baseN + n) * 4);
            const float d0 = fabsf(t0 - r4.x), d1 = fabsf(t1 - r4.y);
            const float d2 = fabsf(t2 - r4.z), d3 = fabsf(t3 - r4.w);
            const float TH = 1.f / 9.f, CC = 0.5f / 9.f;
            reg_sum += (d0 < TH ? 4.5f * d0 * d0 : d0 - CC)
                     + (d1 < TH ? 4.5f * d1 * d1 : d1 - CC)
                     + (d2 < TH ? 4.5f * d2 * d2 : d2 - CC)
                     + (d3 < TH ? 4.5f * d3 * d3 : d3 - CC);
        }
    }

    // 64-lane wave reduce, then cross-wave via LDS
    for (int off = 32; off > 0; off >>= 1) {
        cls_sum += __shfl_down(cls_sum, off);
        reg_sum += __shfl_down(reg_sum, off);
        pos_cnt += __shfl_down(pos_cnt, off);
    }
    __shared__ float s_red[3][THREADS / 64];
    const int wave = threadIdx.x >> 6;
    const int lane = threadIdx.x & 63;
    if (lane == 0) {
        s_red[0][wave] = cls_sum;
        s_red[1][wave] = reg_sum;
        s_red[2][wave] = pos_cnt;
    }
    __syncthreads();
    if (threadIdx.x == 0) {
        float c = 0.f, r = 0.f, p = 0.f;
        #pragma unroll
        for (int w = 0; w < THREADS / 64; ++w) {
            c += s_red[0][w]; r += s_red[1][w]; p += s_red[2][w];
        }
        float* out = partials + ((size_t)b * BPB + blk) * 3;
        out[0] = c; out[1] = r; out[2] = p;
    }
}

__global__ __launch_bounds__(64) void focal_final(
    const float* __restrict__ partials,
    const float* __restrict__ ann,
    float* __restrict__ out)
{
    float cls_l = 0.f, reg_l = 0.f, has = 0.f;
    const int b = threadIdx.x;
    if (b < B) {
        float c = 0.f, r = 0.f, p = 0.f;
        for (int k = 0; k < BPB; ++k) {
            const float* pp = partials + ((size_t)b * BPB + k) * 3;
            c += pp[0]; r += pp[1]; p += pp[2];
        }
        for (int m = 0; m < M; ++m) {
            if (ann[((size_t)b * M + m) * 5 + 4] != -1.f) { has = 1.f; }
        }
        const float npf = fmaxf(p, 1.f);
        if (p > 0.f) {
            cls_l = c / npf;
            reg_l = r / fmaxf(npf * 4.f, 1.f);
        }
        cls_l *= has;
        reg_l *= has;
    }
    for (int off = 32; off > 0; off >>= 1) {
        cls_l += __shfl_down(cls_l, off);
        reg_l += __shfl_down(reg_l, off);
        has   += __shfl_down(has, off);
    }
    if (threadIdx.x == 0) {
        const float denom = fmaxf(has, 1.f);
        out[0] = cls_l / denom;
        out[1] = reg_l / denom;
    }
}

extern "C" void kernel_launch(void* const* d_in, const int* in_sizes, int n_in,
                              void* d_out, int out_size, void* d_ws, size_t ws_size,
                              hipStream_t stream) {
    const float* cls = (const float*)d_in[0];   // [16][100000][10]
    const float* reg = (const float*)d_in[1];   // [16][100000][4]
    const float* anc = (const float*)d_in[2];   // [16][100000][4]
    const float* ann = (const float*)d_in[3];   // [16][32][5]
    float* out = (float*)d_out;                 // 2 fp32 scalars
    float* partials = (float*)d_ws;             // 16*64*3 floats = 12 KB

    focal_main<<<B * BPB, THREADS, 0, stream>>>(cls, reg, anc, ann, partials);
    focal_final<<<1, 64, 0, stream>>>(partials, ann, out);
}